// Round 1
// 78.573 us; speedup vs baseline: 1.0283x; 1.0283x over previous
//
#include <hip/hip_runtime.h>
#include <hip/hip_bf16.h>

// CenterLoss: B=8192 samples, D=512 feat, C=10000 classes.
// out = mean_i clip(||x_i - centers[labels_i]||^2, 1e-12, 1e12)
//
// R1: wave-per-sample + 8192 same-address atomics -> atomic-bound, 108 us.
// R2: block reduction + 256 atomics -> kernel ~11.6 us; bench dominated by
//     harness's 256 MiB d_ws poison fill (~42 us, untouchable).
// R3: no atomics: blocks store partials, 1-wave reduce kernel. 79-81 us total.
// R4: occupancy/latency theory: R3 ran 256 blocks x 512 thr = 2 waves/SIMD,
//     so the label->center dependent-load chain and reduce tail had almost no
//     TLP cover. Now 1 sample/wave, 2048 blocks x 256 thr = 8 waves/SIMD
//     (4x waves, ~40 VGPR, spill-free at launch_bounds(256,8)).
//     Kernel roofline: ~30-34 MB reads @ 6.3 TB/s ~= 5.0-5.3 us.

#define D_FEAT 512
#define THREADS 256          // 4 waves per block
#define WAVES_PER_BLOCK 4
#define BLOCKS 2048          // 2048 * 4 waves * 1 sample/wave = 8192 samples

__global__ __launch_bounds__(THREADS, 8) void center_loss_partial_kernel(
    const float* __restrict__ x,
    const int* __restrict__ labels,
    const float* __restrict__ centers,
    float* __restrict__ partials)
{
    const int wave = threadIdx.x >> 6;
    const int lane = threadIdx.x & 63;
    const int sample = blockIdx.x * WAVES_PER_BLOCK + wave;

    // Wave-uniform label (scalar s_load).
    const int lbl = labels[sample];

    // One sample per wave: 64 lanes x 2 float4 cover the 512-float row.
    const float4* __restrict__ xp =
        (const float4*)(x + (size_t)sample * D_FEAT);
    const float4* __restrict__ cp =
        (const float4*)(centers + (size_t)lbl * D_FEAT);

    // Issue all 4 vector loads before any compute.
    float4 xa = xp[lane];
    float4 xb = xp[lane + 64];
    float4 ca = cp[lane];
    float4 cb = cp[lane + 64];

    float d0 = xa.x - ca.x, d1 = xa.y - ca.y;
    float d2 = xa.z - ca.z, d3 = xa.w - ca.w;
    float d4 = xb.x - cb.x, d5 = xb.y - cb.y;
    float d6 = xb.z - cb.z, d7 = xb.w - cb.w;
    float acc = d0*d0 + d1*d1 + d2*d2 + d3*d3
              + d4*d4 + d5*d5 + d6*d6 + d7*d7;

    // Butterfly: all lanes end with the per-sample total.
    #pragma unroll
    for (int off = 32; off > 0; off >>= 1)
        acc += __shfl_xor(acc, off, 64);
    acc = fminf(fmaxf(acc, 1e-12f), 1e12f);   // per-sample clip

    __shared__ float s_part[WAVES_PER_BLOCK];
    if (lane == 0) s_part[wave] = acc;
    __syncthreads();

    if (threadIdx.x == 0) {
        float block_sum = 0.0f;
        #pragma unroll
        for (int w = 0; w < WAVES_PER_BLOCK; ++w) block_sum += s_part[w];
        partials[blockIdx.x] = block_sum;    // uncontended store, no atomic
    }
}

__global__ __launch_bounds__(64) void center_loss_reduce_kernel(
    const float* __restrict__ partials,
    float* __restrict__ out,
    float inv_B)
{
    const int lane = threadIdx.x;            // 64 lanes x 8 float4 = 2048 floats
    const float4* __restrict__ p = (const float4*)partials;
    float acc = 0.0f;
    #pragma unroll
    for (int k = 0; k < 8; ++k) {
        float4 v = p[lane + 64 * k];
        acc += v.x + v.y + v.z + v.w;
    }
    #pragma unroll
    for (int off = 32; off > 0; off >>= 1)
        acc += __shfl_xor(acc, off, 64);
    if (lane == 0) out[0] = acc * inv_B;
}

extern "C" void kernel_launch(void* const* d_in, const int* in_sizes, int n_in,
                              void* d_out, int out_size, void* d_ws, size_t ws_size,
                              hipStream_t stream) {
    const float* x       = (const float*)d_in[0];
    const int*   labels  = (const int*)d_in[1];
    const float* centers = (const float*)d_in[2];
    float* out      = (float*)d_out;
    float* partials = (float*)d_ws;          // 2048 floats of scratch

    const int B = in_sizes[1];               // 8192

    center_loss_partial_kernel<<<BLOCKS, THREADS, 0, stream>>>(
        x, labels, centers, partials);
    center_loss_reduce_kernel<<<1, 64, 0, stream>>>(
        partials, out, 1.0f / (float)B);
}